// Round 10
// baseline (980.574 us; speedup 1.0000x reference)
//
#include <hip/hip_runtime.h>

// Fused entmax(alpha=1.3) attention, fp32. B=16, N=2048, D=64.
// R9 = R8b MFMA front-end (verified correct: Output 0 passed, so scores/
// lists/solver/PV are right) + the R7-PROVEN attn-write epilogue (segmented
// 1024-float prow, f32x4 LDS zero, guarded scalar scatter, SCALAR
// nontemporal stream + compiler fences). R8b's whole-row compose with
// 16-B vector nontemporal stores was the only unproven piece in its
// failure (attn absmax 1.0 with out passing) — reverted to scalar-nt.
// Front-end: bf16 3-product split scores (qh*kh+ql*kh+qh*kl), pass1 = row
// max (hi*hi; any max error only shifts the compaction threshold, never
// drops support), pass2 = split-precise + ballot-compact actives
// (> max-1.02) into per-row lists. A>64 -> dense fp32 fallback.

typedef __attribute__((ext_vector_type(8))) short short8;
typedef __attribute__((ext_vector_type(4))) float f32x4;

#define NB 16
#define NS 2048
#define DH 64
#define OUT_OFF (NB * NS * DH)     // out first, attn second
#define INV_A    3.3333333f        // 1/(alpha-1)
#define INV_A_M1 2.3333333f
#define TK    128                  // K-tile rows
#define KSTR  72                   // shorts per LDS K row
#define NTILE (NS / TK)            // 16
#define MAXA  64                   // compact-list capacity per row

__device__ __forceinline__ float fast_log2(float x) { return __builtin_amdgcn_logf(x); }
__device__ __forceinline__ float fast_exp2(float x) { return __builtin_amdgcn_exp2f(x); }

__device__ __forceinline__ unsigned f2bf(float x) {   // RNE f32 -> bf16 bits
    union { float f; unsigned u; } c; c.f = x;
    return (c.u + 0x7FFFu + ((c.u >> 16) & 1u)) >> 16;
}
__device__ __forceinline__ float bf2f(unsigned h) {
    union { float f; unsigned u; } c; c.u = h << 16;
    return c.f;
}
__device__ __forceinline__ uint4 packhi8(float4 a, float4 b) {
    uint4 r;
    r.x = f2bf(a.x) | (f2bf(a.y) << 16);
    r.y = f2bf(a.z) | (f2bf(a.w) << 16);
    r.z = f2bf(b.x) | (f2bf(b.y) << 16);
    r.w = f2bf(b.z) | (f2bf(b.w) << 16);
    return r;
}
__device__ __forceinline__ float4 res4(float4 a) {    // a - bf16(a)
    float4 r;
    r.x = a.x - bf2f(f2bf(a.x));
    r.y = a.y - bf2f(f2bf(a.y));
    r.z = a.z - bf2f(f2bf(a.z));
    r.w = a.w - bf2f(f2bf(a.w));
    return r;
}

__global__ __launch_bounds__(256) void entmax_attn_kernel(
    const float* __restrict__ Q, const float* __restrict__ K,
    const float* __restrict__ V, float* __restrict__ Out)
{
    __shared__ __align__(16) unsigned short kls[2][TK * KSTR];  // K hi|lo tiles
    __shared__ __align__(16) float          vlist[64][MAXA];
    __shared__ unsigned short               ilist[64][MAXA];
    __shared__ int                          cnt[64];

    const int tid  = threadIdx.x;
    const int w    = tid >> 6;
    const int lane = tid & 63;
    const int quad = lane >> 4;
    const int col  = lane & 15;

    // XCD pinning: batch b -> XCD b%8 (K/V of 2 batches L2-resident)
    const int i  = blockIdx.x;              // 0..511
    const int b  = (i & 7) + 8 * ((i >> 3) & 1);
    const int rb = i >> 4;                  // 0..31
    const int n0 = rb * 64;                 // block covers q rows n0..n0+63

    const float* Qb = Q + (size_t)b * NS * DH;
    const float* Kb = K + (size_t)b * NS * DH;
    const float* Vb = V + (size_t)b * NS * DH;

    unsigned short* khi = kls[0];
    unsigned short* klo = kls[1];

    // A-fragments: wave w owns q-rows n0+16w..+15. A[m=lane&15][k=quad*8+j]
    short8 qh[2], ql[2];
    {
        const float* qp = Qb + (size_t)(n0 + w * 16 + col) * DH + quad * 8;
        #pragma unroll
        for (int c = 0; c < 2; ++c) {
            const float4 a  = *(const float4*)(qp + c * 32);
            const float4 b4 = *(const float4*)(qp + c * 32 + 4);
            qh[c] = __builtin_bit_cast(short8, packhi8(a, b4));
            ql[c] = __builtin_bit_cast(short8, packhi8(res4(a), res4(b4)));
        }
    }

    // ---------------- pass 1: row maxima (hi*hi only) ----------------
    float rmx[4] = {-3.0e38f, -3.0e38f, -3.0e38f, -3.0e38f};
    #pragma unroll 1
    for (int t = 0; t < NTILE; ++t) {
        __syncthreads();
        {   // stage hi tile (coalesced)
            const int row = tid >> 1, half = tid & 1;
            const float* src = Kb + (size_t)(t * TK + row) * DH + half * 32;
            unsigned short* dh = &khi[row * KSTR + half * 32];
            #pragma unroll
            for (int g = 0; g < 4; ++g) {
                const float4 a  = ((const float4*)src)[2 * g];
                const float4 b4 = ((const float4*)src)[2 * g + 1];
                *(uint4*)&dh[g * 8] = packhi8(a, b4);
            }
        }
        __syncthreads();
        #pragma unroll 1
        for (int mt = 0; mt < TK / 16; ++mt) {
            const unsigned short* kp = &khi[(mt * 16 + col) * KSTR + quad * 8];
            const short8 b0 = *(const short8*)kp;
            const short8 b1 = *(const short8*)(kp + 32);
            f32x4 acc = {0.f, 0.f, 0.f, 0.f};
            acc = __builtin_amdgcn_mfma_f32_16x16x32_bf16(qh[0], b0, acc, 0, 0, 0);
            acc = __builtin_amdgcn_mfma_f32_16x16x32_bf16(qh[1], b1, acc, 0, 0, 0);
            rmx[0] = fmaxf(rmx[0], acc[0]);
            rmx[1] = fmaxf(rmx[1], acc[1]);
            rmx[2] = fmaxf(rmx[2], acc[2]);
            rmx[3] = fmaxf(rmx[3], acc[3]);
        }
    }
    // C layout: row = quad*4 + r, col = lane&15 -> reduce over cols (bits 0..3)
    #pragma unroll
    for (int off = 1; off <= 8; off <<= 1) {
        rmx[0] = fmaxf(rmx[0], __shfl_xor(rmx[0], off, 64));
        rmx[1] = fmaxf(rmx[1], __shfl_xor(rmx[1], off, 64));
        rmx[2] = fmaxf(rmx[2], __shfl_xor(rmx[2], off, 64));
        rmx[3] = fmaxf(rmx[3], __shfl_xor(rmx[3], off, 64));
    }
    const float thr0 = rmx[0] - 8.16f;   // c-units: s-mx > -1.02
    const float thr1 = rmx[1] - 8.16f;
    const float thr2 = rmx[2] - 8.16f;
    const float thr3 = rmx[3] - 8.16f;
    if (tid < 64) cnt[tid] = 0;

    // ---------------- pass 2: split-precise scores + compaction ------------
    const unsigned lt16 = (1u << col) - 1u;
    #pragma unroll 1
    for (int t = 0; t < NTILE; ++t) {
        __syncthreads();
        {   // stage hi + lo
            const int row = tid >> 1, half = tid & 1;
            const float* src = Kb + (size_t)(t * TK + row) * DH + half * 32;
            unsigned short* dh = &khi[row * KSTR + half * 32];
            unsigned short* dl = &klo[row * KSTR + half * 32];
            #pragma unroll
            for (int g = 0; g < 4; ++g) {
                const float4 a  = ((const float4*)src)[2 * g];
                const float4 b4 = ((const float4*)src)[2 * g + 1];
                *(uint4*)&dh[g * 8] = packhi8(a, b4);
                *(uint4*)&dl[g * 8] = packhi8(res4(a), res4(b4));
            }
        }
        __syncthreads();
        #pragma unroll 1
        for (int mt = 0; mt < TK / 16; ++mt) {
            const unsigned short* kp = &khi[(mt * 16 + col) * KSTR + quad * 8];
            const unsigned short* lp = &klo[(mt * 16 + col) * KSTR + quad * 8];
            const short8 b0h = *(const short8*)kp;
            const short8 b1h = *(const short8*)(kp + 32);
            const short8 b0l = *(const short8*)lp;
            const short8 b1l = *(const short8*)(lp + 32);
            f32x4 acc = {0.f, 0.f, 0.f, 0.f};
            acc = __builtin_amdgcn_mfma_f32_16x16x32_bf16(qh[0], b0h, acc, 0, 0, 0);
            acc = __builtin_amdgcn_mfma_f32_16x16x32_bf16(qh[1], b1h, acc, 0, 0, 0);
            acc = __builtin_amdgcn_mfma_f32_16x16x32_bf16(ql[0], b0h, acc, 0, 0, 0);
            acc = __builtin_amdgcn_mfma_f32_16x16x32_bf16(ql[1], b1h, acc, 0, 0, 0);
            acc = __builtin_amdgcn_mfma_f32_16x16x32_bf16(qh[0], b0l, acc, 0, 0, 0);
            acc = __builtin_amdgcn_mfma_f32_16x16x32_bf16(qh[1], b1l, acc, 0, 0, 0);
            #pragma unroll
            for (int r = 0; r < 4; ++r) {
                const float cr  = acc[r];
                const float tr  = (r == 0) ? thr0 : (r == 1) ? thr1 : (r == 2) ? thr2 : thr3;
                const float mr  = (r == 0) ? rmx[0] : (r == 1) ? rmx[1] : (r == 2) ? rmx[2] : rmx[3];
                const bool act  = cr > tr;
                const unsigned long long bm = __ballot(act);
                if (bm) {
                    const unsigned my = (unsigned)(bm >> (quad * 16)) & 0xFFFFu;
                    const int lrow = w * 16 + quad * 4 + r;   // wave-local rows disjoint
                    const int base = cnt[lrow];               // same-wave RAW
                    const int pos  = base + __popc(my & lt16);
                    if (act && pos < MAXA) {
                        vlist[lrow][pos] = (cr - mr) * 0.125f;
                        ilist[lrow][pos] = (unsigned short)(t * TK + mt * 16 + col);
                    }
                    if (col == 0) cnt[lrow] = base + __popc(my);
                }
            }
        }
    }
    __syncthreads();   // K tiles dead -> kls becomes per-wave prow buffers

    float* prow = (float*)kls + w * 2048;   // 1024 floats used per segment

    // ---------------- per-row: solve + attn write (R7 pattern) + PV --------
    #pragma unroll 1
    for (int rr = 0; rr < 16; ++rr) {
        const int lrow = w * 16 + rr;
        const int n    = n0 + lrow;
        const int A    = cnt[lrow];            // wave-uniform
        float* arow = Out + OUT_OFF + ((size_t)b * NS + n) * NS;
        float  oa = 0.f;

        if (A <= MAXA) {
            const bool ok = lane < A;
            const float v = ok ? vlist[lrow][lane] : -2.0f;
            const int   e = ok ? (int)ilist[lrow][lane] : 0;

            float m2 = v;                      // exact listed max (= row max, shifted)
            #pragma unroll
            for (int off = 1; off <= 32; off <<= 1) m2 = fmaxf(m2, __shfl_xor(m2, off, 64));
            float lo = m2 - 1.0f, hi = m2 - 1e-6f;
            #pragma unroll 1
            for (int it = 0; it < 12; ++it) {
                const float tau = 0.5f * (lo + hi);
                const float tt  = v - tau;
                float S = (ok && tt > 0.f) ? fast_exp2(INV_A * fast_log2(tt)) : 0.f;
                #pragma unroll
                for (int off = 1; off <= 32; off <<= 1) S += __shfl_xor(S, off, 64);
                if (S > 1.f) lo = tau; else hi = tau;
            }
            float tau = lo;
            #pragma unroll 1
            for (int it = 0; it < 2; ++it) {   // Newton from left: monotone-safe
                const float tt = v - tau;
                float S1 = 0.f, S2 = 0.f;
                if (ok && tt > 0.f) {
                    const float l = fast_log2(tt);
                    S1 = fast_exp2(INV_A * l);
                    S2 = fast_exp2(INV_A_M1 * l);
                }
                #pragma unroll
                for (int off = 1; off <= 32; off <<= 1) {
                    S1 += __shfl_xor(S1, off, 64);
                    S2 += __shfl_xor(S2, off, 64);
                }
                tau += (S1 - 1.f) / (INV_A * S2);
                tau = fmaxf(fminf(tau, hi), lo);
            }
            const float tf = v - tau;
            float p = (ok && tf > 0.f) ? fast_exp2(INV_A * fast_log2(tf)) : 0.f;
            float S = p;
            #pragma unroll
            for (int off = 1; off <= 32; off <<= 1) S += __shfl_xor(S, off, 64);
            const float pn = p / (S + 1e-12f);
            if (ok) vlist[lrow][lane] = pn;    // list now holds normalized p

            // R7-proven attn write: 2 x 1024-float segments, scalar nt stream
            #pragma unroll
            for (int seg = 0; seg < 2; ++seg) {
                #pragma unroll
                for (int z = 0; z < 4; ++z)
                    *(f32x4*)&prow[(z * 64 + lane) * 4] = (f32x4){0.f, 0.f, 0.f, 0.f};
                asm volatile("" ::: "memory");
                if (ok && (e >> 10) == seg) prow[e & 1023] = pn;
                asm volatile("" ::: "memory");
                #pragma unroll
                for (int z = 0; z < 16; ++z)
                    __builtin_nontemporal_store(prow[z * 64 + lane],
                                                &arow[seg * 1024 + z * 64 + lane]);
            }

            // sparse PV over the active V rows; out dim d = lane
            int ii = 0;
            #pragma unroll 1
            for (; ii + 2 <= A; ii += 2) {
                const float p0 = vlist[lrow][ii], p1 = vlist[lrow][ii + 1];
                const int   m0 = ilist[lrow][ii], m1 = ilist[lrow][ii + 1];
                oa += p0 * Vb[(size_t)m0 * DH + lane] + p1 * Vb[(size_t)m1 * DH + lane];
            }
            if (ii < A) oa += vlist[lrow][ii] * Vb[(size_t)ilist[lrow][ii] * DH + lane];
        } else {
            // -------- dense fp32 fallback (R7 epilogue pattern) -------------
            const float* Qr = Qb + (size_t)n * DH;
            float s[32];
            #pragma unroll
            for (int j = 0; j < 32; ++j) {
                const float* kr = Kb + (size_t)(j * 64 + lane) * DH;
                float d = 0.f;
                #pragma unroll 1
                for (int g = 0; g < 16; ++g) {
                    const float4 qv = ((const float4*)Qr)[g];
                    const float4 kv = ((const float4*)kr)[g];
                    d += qv.x * kv.x + qv.y * kv.y + qv.z * kv.z + qv.w * kv.w;
                }
                s[j] = d * 0.125f;
            }
            float mx = s[0];
            #pragma unroll
            for (int j = 1; j < 32; ++j) mx = fmaxf(mx, s[j]);
            #pragma unroll
            for (int off = 1; off <= 32; off <<= 1) mx = fmaxf(mx, __shfl_xor(mx, off, 64));
            #pragma unroll
            for (int j = 0; j < 32; ++j) s[j] -= mx;
            float lo = -1.0f, hi = -1e-6f;
            #pragma unroll 1
            for (int it = 0; it < 12; ++it) {
                const float tau = 0.5f * (lo + hi);
                float S = 0.f;
                #pragma unroll
                for (int j = 0; j < 32; ++j) {
                    const float tt = s[j] - tau;
                    S += (tt > 0.f) ? fast_exp2(INV_A * fast_log2(tt)) : 0.f;
                }
                #pragma unroll
                for (int off = 1; off <= 32; off <<= 1) S += __shfl_xor(S, off, 64);
                if (S > 1.f) lo = tau; else hi = tau;
            }
            float tau = lo;
            #pragma unroll 1
            for (int it = 0; it < 2; ++it) {
                float S1 = 0.f, S2 = 0.f;
                #pragma unroll
                for (int j = 0; j < 32; ++j) {
                    const float tt = s[j] - tau;
                    if (tt > 0.f) {
                        const float l = fast_log2(tt);
                        S1 += fast_exp2(INV_A * l);
                        S2 += fast_exp2(INV_A_M1 * l);
                    }
                }
                #pragma unroll
                for (int off = 1; off <= 32; off <<= 1) {
                    S1 += __shfl_xor(S1, off, 64);
                    S2 += __shfl_xor(S2, off, 64);
                }
                tau += (S1 - 1.f) / (INV_A * S2);
                tau = fmaxf(fminf(tau, hi), lo);
            }
            float S = 0.f;
            #pragma unroll
            for (int j = 0; j < 32; ++j) {
                const float tt = s[j] - tau;
                const float p = (tt > 0.f) ? fast_exp2(INV_A * fast_log2(tt)) : 0.f;
                s[j] = p;
                S += p;
            }
            #pragma unroll
            for (int off = 1; off <= 32; off <<= 1) S += __shfl_xor(S, off, 64);
            const float rnorm = 1.f / (S + 1e-12f);

            #pragma unroll
            for (int seg = 0; seg < 2; ++seg) {
                #pragma unroll
                for (int jj = 0; jj < 16; ++jj)
                    prow[jj * 64 + lane] = s[seg * 16 + jj] * rnorm;
                asm volatile("" ::: "memory");
                #pragma unroll
                for (int z = 0; z < 16; ++z)
                    __builtin_nontemporal_store(prow[z * 64 + lane],
                                                &arow[seg * 1024 + z * 64 + lane]);
                #pragma unroll 4
                for (int m = 0; m < 1024; ++m)
                    oa += prow[m] * Vb[(size_t)(seg * 1024 + m) * DH + lane];
            }
        }
        Out[((size_t)b * NS + n) * DH + lane] = oa;
    }
}

extern "C" void kernel_launch(void* const* d_in, const int* in_sizes, int n_in,
                              void* d_out, int out_size, void* d_ws, size_t ws_size,
                              hipStream_t stream) {
    const float* q = (const float*)d_in[0];
    const float* k = (const float*)d_in[1];
    const float* v = (const float*)d_in[2];
    float* out = (float*)d_out;
    (void)in_sizes; (void)n_in; (void)out_size; (void)d_ws; (void)ws_size;
    dim3 grid(512), block(256);
    hipLaunchKernelGGL(entmax_attn_kernel, grid, block, 0, stream, q, k, v, out);
}